// Round 12
// baseline (2198.321 us; speedup 1.0000x reference)
//
#include <hip/hip_runtime.h>
#include <cstdint>
#include <cstddef>

namespace {

constexpr int NN   = 200000;   // nodes
constexpr int NE   = 800000;   // edges
constexpr int NG   = 4096;     // graphs
constexpr int MAXD = 5;

constexpr int BM = 64;
constexpr int KT = 32;
constexpr int NBC = (NN + 255) / 256;           // 782 preprocessing blocks
constexpr int NBLK  = (NN + BM - 1) / BM + 6;   // 3131 (bucket padding)
constexpr int PERMN = NBLK * BM;                // 200384

typedef _Float16 half8 __attribute__((ext_vector_type(8)));
typedef _Float16 half4 __attribute__((ext_vector_type(4)));
typedef float    f32x4 __attribute__((ext_vector_type(4)));

// packed-weight offsets (fragment-ordered, per layer: 6 * 2*CIN * COUT elems)
constexpr size_t P_L0 = (size_t)6 * 128 * 128;   // 98304
constexpr size_t P_L1 = (size_t)6 * 256 * 128;   // 196608
constexpr size_t P_L2 = (size_t)6 * 256 * 256;   // 393216
constexpr size_t P_L3 = (size_t)6 * 512 * 256;   // 786432
constexpr size_t O_P0 = 0;
constexpr size_t O_P1 = O_P0 + P_L0;
constexpr size_t O_P2 = O_P1 + P_L1;
constexpr size_t O_P3 = O_P2 + P_L2;
constexpr size_t WTOT = O_P3 + P_L3;             // 1,474,560 elements

// ---------------- init / diagnostic ----------------

__global__ void k_memset32(int* __restrict__ p, int v, int n) {
    int i = blockIdx.x * 256 + threadIdx.x;
    if (i < n) p[i] = v;
}

__global__ void k_report(float* __restrict__ outp, float v, int n) {
    int i = blockIdx.x * 256 + threadIdx.x;
    if (i < n) outp[i] = v;
}

// pack fp32 weights into MFMA B-fragment order, f16 hi/lo split.
template <int CIN, int COUT>
__global__ void k_wpack(const float* __restrict__ Wl, const float* __restrict__ Wr,
                        _Float16* __restrict__ hi, _Float16* __restrict__ lo) {
    constexpr int NT = CIN / 16;   // tiles over k = 2*CIN
    constexpr int NB = COUT / 16;
    const int total = 6 * NT * NB * 64;
    int idx = blockIdx.x * 256 + threadIdx.x;
    if (idx >= total) return;
    const int lane = idx & 63;
    int rest = idx >> 6;
    const int nb = rest % NB; rest /= NB;
    const int ti = rest % NT;
    const int d  = rest / NT;
    const int k0 = ti * 32 + ((lane >> 4) * 8);
    const int n  = nb * 16 + (lane & 15);
    half8 hv, lv;
#pragma unroll
    for (int j = 0; j < 8; j++) {
        const int kk = k0 + j;
        const float v = (kk < CIN)
                            ? Wl[((size_t)d * CIN + kk) * COUT + n]
                            : Wr[((size_t)d * CIN + (kk - CIN)) * COUT + n];
        const _Float16 h = (_Float16)v;
        hv[j] = h;
        lv[j] = (_Float16)(v - (float)h);
    }
    *(half8*)(hi + (size_t)idx * 8) = hv;
    *(half8*)(lo + (size_t)idx * 8) = lv;
}

// ---------------- graph preprocessing ----------------

__global__ void k_count_deg(const int* __restrict__ dst, int* __restrict__ deg) {
    int e = blockIdx.x * 256 + threadIdx.x;
    if (e < NE) atomicAdd(&deg[dst[e]], 1);
}

__global__ void k_scan_part(const int* __restrict__ deg, int* __restrict__ part) {
    __shared__ int s[256];
    int t = threadIdx.x, i = blockIdx.x * 256 + t;
    s[t] = (i < NN) ? deg[i] : 0;
    __syncthreads();
    for (int st = 128; st > 0; st >>= 1) {
        if (t < st) s[t] += s[t + st];
        __syncthreads();
    }
    if (t == 0) part[blockIdx.x] = s[0];
}

__global__ void k_scan_single(int* __restrict__ part, int nb) {
    __shared__ int s[1024];
    int t = threadIdx.x;
    int v0 = (t < nb) ? part[t] : 0;
    s[t] = v0;
    __syncthreads();
    for (int off = 1; off < 1024; off <<= 1) {
        int v = (t >= off) ? s[t - off] : 0;
        __syncthreads();
        s[t] += v;
        __syncthreads();
    }
    if (t < nb) part[t] = s[t] - v0;
}

__global__ void k_scan_final(const int* __restrict__ deg, const int* __restrict__ part,
                             int* __restrict__ row_ptr, int* __restrict__ cursor) {
    __shared__ int s[256];
    int t = threadIdx.x, i = blockIdx.x * 256 + t;
    int v0 = (i < NN) ? deg[i] : 0;
    s[t] = v0;
    __syncthreads();
    for (int off = 1; off < 256; off <<= 1) {
        int v = (t >= off) ? s[t - off] : 0;
        __syncthreads();
        s[t] += v;
        __syncthreads();
    }
    if (i < NN) {
        int excl = s[t] - v0 + part[blockIdx.x];
        row_ptr[i] = excl;
        cursor[i]  = excl;
        if (i == NN - 1) row_ptr[NN] = excl + v0;
    }
}

__global__ void k_fill_csr(const int* __restrict__ src, const int* __restrict__ dst,
                           int* __restrict__ cursor, int* __restrict__ col) {
    int e = blockIdx.x * 256 + threadIdx.x;
    if (e < NE) {
        int d = dst[e];
        int slot = atomicAdd(&cursor[d], 1);
        col[slot] = src[e];
    }
}

// -- two-level bucket counting sort (decontended; round-9 fix) --

__global__ void k_bucket_blockcount(const int* __restrict__ deg, int* __restrict__ blkcnt) {
    __shared__ int h[6];
    int t = threadIdx.x;
    if (t < 6) h[t] = 0;
    __syncthreads();
    int i = blockIdx.x * 256 + t;
    if (i < NN) atomicAdd(&h[min(deg[i], MAXD)], 1);
    __syncthreads();
    if (t < 6) blkcnt[t * NBC + blockIdx.x] = h[t];
}

__global__ void k_bucket_scanall(int* __restrict__ blkcnt, int* __restrict__ bpad) {
    __shared__ int tot[6];
    int t = threadIdx.x;
    if (t < 6) {
        int run = 0;
        for (int j = 0; j < NBC; j++) {
            int v = blkcnt[t * NBC + j];
            blkcnt[t * NBC + j] = run;
            run += v;
        }
        tot[t] = run;
    }
    __syncthreads();
    if (t == 0) {
        int off = 0;
        for (int b = 0; b < 6; b++) {
            bpad[b] = off;
            off += ((tot[b] + BM - 1) / BM) * BM;
        }
        bpad[6] = off;
    }
}

__global__ void k_scatter2(const int* __restrict__ deg, const int* __restrict__ blkcnt,
                           const int* __restrict__ bpad, int* __restrict__ perm) {
    __shared__ int base[6];
    int t = threadIdx.x;
    if (t < 6) base[t] = bpad[t] + blkcnt[t * NBC + blockIdx.x];
    __syncthreads();
    int i = blockIdx.x * 256 + t;
    if (i < NN) {
        int b = min(deg[i], MAXD);
        int pos = atomicAdd(&base[b], 1);
        perm[pos] = i;
    }
}

// ---------------- layer-2a: plain neighbor-sum aggregate ----------------

__global__ void k_aggregate128(const float* __restrict__ hin, const int* __restrict__ row_ptr,
                               const int* __restrict__ col, float* __restrict__ msg) {
    int node = blockIdx.x * 4 + (threadIdx.x >> 6);
    int lane = threadIdx.x & 63;
    int s = row_ptr[node], e = row_ptr[node + 1];
    float2 acc = make_float2(0.f, 0.f);
    for (int p = s; p < e; p++) {
        const float2 v = *(const float2*)(hin + (size_t)col[p] * 128 + lane * 2);
        acc.x += v.x; acc.y += v.y;
    }
    *(float2*)(msg + (size_t)node * 128 + lane * 2) = acc;
}

// ---------------- fused aggregate + transform (fragment-native MFMA) --------

// out[i] = [sum_{j->i} hin[j], hin[i]] @ [Wl[d]; Wr[d]] + bl[d], d = bucket(i).
// A staged in LDS in MFMA-fragment order; B loaded pre-packed global->reg.
// Edge-offset cache: up to 8 col[p]*stride values preloaded into constant-
// indexed registers before the K-loop, so per-tile gathers have a 1-level
// load chain (round-11: 2-level col->data chain at 30% occupancy = 672 us).
// 3-pass f16 hi/lo split MFMA; gather prefetch pipeline retained.
template <int C0, int C1, int COUT, int BN_, bool POOL_FUSE>
__launch_bounds__(256, 4)
__global__ void k_transform(const float* __restrict__ hin0, const float* __restrict__ hin1,
                            const int* __restrict__ row_ptr, const int* __restrict__ col,
                            const _Float16* __restrict__ wph, const _Float16* __restrict__ wpl,
                            const float* __restrict__ bias, const float* __restrict__ Wf,
                            const int* __restrict__ perm, const int* __restrict__ deg,
                            const int* __restrict__ batch,
                            float* __restrict__ out0, float* __restrict__ pool,
                            float* __restrict__ logits, int wf_off) {
    constexpr int CIN = C0 + C1;
    constexpr int NW0 = C0 / 32;
    constexpr int NW  = CIN / 32;
    constexpr int NT  = 2 * NW;
    constexpr int NB  = COUT / 16;
    constexpr int NTN = BN_ / 64;        // n-tiles per wave
    static_assert(C1 == 0 || C1 == C0, "edge-offset cache needs uniform stride");
    constexpr int STRIDE = C0;
    __shared__ _Float16 Ah[4][64][8];    // 4 KB
    __shared__ _Float16 Al[4][64][8];    // 4 KB
    __shared__ int rowid[BM];

    const int t  = threadIdx.x;
    const int m0 = blockIdx.x * BM;
    const int n0 = blockIdx.y * BN_;

    if (t < BM) rowid[t] = perm[m0 + t];
    __syncthreads();
    if (rowid[0] < 0) return;  // fully-padded block (uniform exit)

    const int d = min(deg[rowid[0]], MAXD);

    const int am = t & 63, aq = t >> 6;
    const int anode = rowid[am];
    int es = 0, ee = 0;
    if (anode >= 0) { es = row_ptr[anode]; ee = row_ptr[anode + 1]; }
    const int ndeg = ee - es;
    const int lx = t & 15, qd = (t >> 4) & 3, wv = t >> 6;

    // edge-offset register cache (constant-indexed; predicated init)
    int eoff[8];
#pragma unroll
    for (int i = 0; i < 8; i++)
        eoff[i] = (i < ndeg) ? col[es + i] * STRIDE : 0;

    // A-fragment write targets for this thread (k-slices 4aq and 16+4aq)
    const int mt_w = am >> 4;
    const int lA1  = (am & 15) + ((aq >> 1) << 4);
    const int lA2  = (am & 15) + ((2 + (aq >> 1)) << 4);
    const int j0   = (aq & 1) * 4;

    const int nb0 = n0 / 16 + wv * NTN;

    // gather A-fragment for tile ti into g[8] (constant-indexed scalars)
    auto gather = [&](int ti, float* g) {
#pragma unroll
        for (int i = 0; i < 8; i++) g[i] = 0.f;
        if (ti < NW) {
            const bool lo = (C1 == 0) || (ti < NW0);
            const float* base = lo ? hin0 : hin1;
            const int off = (lo ? 32 * ti : 32 * (ti - NW0)) + 4 * aq;
#pragma unroll
            for (int i = 0; i < 8; i++) {
                if (i < ndeg) {
                    const float* r = base + (size_t)(unsigned)eoff[i] + off;
                    const float4 a = *(const float4*)r;
                    const float4 b = *(const float4*)(r + 16);
                    g[0] += a.x; g[1] += a.y; g[2] += a.z; g[3] += a.w;
                    g[4] += b.x; g[5] += b.y; g[6] += b.z; g[7] += b.w;
                }
            }
            for (int p = es + 8; p < ee; p++) {   // rare tail (deg > 8)
                const float* r = base + (size_t)col[p] * STRIDE + off;
                const float4 a = *(const float4*)r;
                const float4 b = *(const float4*)(r + 16);
                g[0] += a.x; g[1] += a.y; g[2] += a.z; g[3] += a.w;
                g[4] += b.x; g[5] += b.y; g[6] += b.z; g[7] += b.w;
            }
        } else if (anode >= 0) {
            const int e = (ti - NW) * 32 + 4 * aq;
            const float* r = (C1 == 0 || e < C0)
                                 ? hin0 + (size_t)anode * C0 + e
                                 : hin1 + (size_t)anode * C1 + (e - C0);
            const float4 a = *(const float4*)r;
            const float4 b = *(const float4*)(r + 16);
            g[0] = a.x; g[1] = a.y; g[2] = a.z; g[3] = a.w;
            g[4] = b.x; g[5] = b.y; g[6] = b.z; g[7] = b.w;
        }
    };

    f32x4 acc[4][NTN];
#pragma unroll
    for (int mt = 0; mt < 4; mt++)
#pragma unroll
        for (int nt = 0; nt < NTN; nt++) acc[mt][nt] = (f32x4)0.f;

    float gcur[8];
    gather(0, gcur);

    for (int ti = 0; ti < NT; ti++) {
        // stage A (fp32 -> f16 hi/lo, fragment layout)
        {
            half4 h1, l1, h2, l2;
#pragma unroll
            for (int i = 0; i < 4; i++) {
                const _Float16 h = (_Float16)gcur[i];
                h1[i] = h; l1[i] = (_Float16)(gcur[i] - (float)h);
                const _Float16 g = (_Float16)gcur[4 + i];
                h2[i] = g; l2[i] = (_Float16)(gcur[4 + i] - (float)g);
            }
            *(half4*)&Ah[mt_w][lA1][j0] = h1;
            *(half4*)&Al[mt_w][lA1][j0] = l1;
            *(half4*)&Ah[mt_w][lA2][j0] = h2;
            *(half4*)&Al[mt_w][lA2][j0] = l2;
        }
        // B fragments: global -> reg (pre-packed, coalesced)
        half8 bh[NTN], bl[NTN];
        {
            const size_t tbase = (((size_t)d * NT + ti) * NB) * 512;
#pragma unroll
            for (int nt = 0; nt < NTN; nt++) {
                const size_t off = tbase + (size_t)(nb0 + nt) * 512 + (size_t)am * 8;
                bh[nt] = *(const half8*)(wph + off);
                bl[nt] = *(const half8*)(wpl + off);
            }
        }
        __syncthreads();

        // prefetch next tile's fragment (overlaps MFMA below)
        float gnext[8];
        if (ti + 1 < NT) {
            gather(ti + 1, gnext);
        } else {
#pragma unroll
            for (int i = 0; i < 8; i++) gnext[i] = 0.f;
        }

        // MFMA 3-pass over tile ti
        {
            half8 ah[4], alo[4];
#pragma unroll
            for (int mt = 0; mt < 4; mt++) {
                ah[mt]  = *(const half8*)&Ah[mt][am][0];
                alo[mt] = *(const half8*)&Al[mt][am][0];
            }
#pragma unroll
            for (int nt = 0; nt < NTN; nt++)
#pragma unroll
                for (int mt = 0; mt < 4; mt++) {
                    acc[mt][nt] = __builtin_amdgcn_mfma_f32_16x16x32_f16(ah[mt],  bh[nt], acc[mt][nt], 0, 0, 0);
                    acc[mt][nt] = __builtin_amdgcn_mfma_f32_16x16x32_f16(alo[mt], bh[nt], acc[mt][nt], 0, 0, 0);
                    acc[mt][nt] = __builtin_amdgcn_mfma_f32_16x16x32_f16(ah[mt],  bl[nt], acc[mt][nt], 0, 0, 0);
                }
        }
        __syncthreads();

#pragma unroll
        for (int i = 0; i < 8; i++) gcur[i] = gnext[i];
    }

    // epilogue: lane cols are n0 + wv*16*NTN + nt*16 + lx
    float blv[NTN], w0[NTN], w1[NTN];
    int cols[NTN];
#pragma unroll
    for (int nt = 0; nt < NTN; nt++) {
        cols[nt] = n0 + wv * (16 * NTN) + nt * 16 + lx;
        blv[nt] = bias[d * COUT + cols[nt]];
        w0[nt]  = Wf[(size_t)(wf_off + cols[nt]) * 2 + 0];
        w1[nt]  = Wf[(size_t)(wf_off + cols[nt]) * 2 + 1];
    }
#pragma unroll
    for (int mt = 0; mt < 4; mt++)
#pragma unroll
    for (int r = 0; r < 4; r++) {
        const int node = rowid[mt * 16 + qd * 4 + r];
        float p0 = 0.f, p1 = 0.f;
        if (node >= 0) {
            float h[NTN];
#pragma unroll
            for (int nt = 0; nt < NTN; nt++) {
                h[nt] = acc[mt][nt][r] + blv[nt];
                p0 = fmaf(h[nt], w0[nt], p0);
                p1 = fmaf(h[nt], w1[nt], p1);
            }
            if constexpr (POOL_FUSE) {
                float* pr = pool + (size_t)batch[node] * 256;
#pragma unroll
                for (int nt = 0; nt < NTN; nt++) atomicAdd(&pr[cols[nt]], h[nt]);
            } else {
                float* orow = out0 + (size_t)node * COUT;
#pragma unroll
                for (int nt = 0; nt < NTN; nt++) orow[cols[nt]] = h[nt];
            }
        }
#pragma unroll
        for (int s = 1; s < 16; s <<= 1) {
            p0 += __shfl_xor(p0, s, 64);
            p1 += __shfl_xor(p1, s, 64);
        }
        if (node >= 0 && lx == 0) {
            atomicAdd(&logits[(size_t)node * 2 + 0], p0);
            atomicAdd(&logits[(size_t)node * 2 + 1], p1);
        }
    }
}

// ---------------- layer-2b: full-width MFMA GEMM, in-place ----------------

__launch_bounds__(256, 4)
__global__ void k_gemm2b(float* __restrict__ buf0, float* __restrict__ buf1,
                         const _Float16* __restrict__ wph, const _Float16* __restrict__ wpl,
                         const float* __restrict__ bias, const float* __restrict__ Wf,
                         const int* __restrict__ perm, const int* __restrict__ deg,
                         float* __restrict__ logits) {
    constexpr int COUT = 256, NT = 8, NB = 16, NTN = 4;
    __shared__ _Float16 Ah[4][64][8];
    __shared__ _Float16 Al[4][64][8];
    __shared__ int rowid[BM];

    const int t  = threadIdx.x;
    const int m0 = blockIdx.x * BM;

    if (t < BM) rowid[t] = perm[m0 + t];
    __syncthreads();
    if (rowid[0] < 0) return;

    const int d = min(deg[rowid[0]], MAXD);

    const int am = t & 63, aq = t >> 6;
    const int anode = rowid[am];
    const int lx = t & 15, qd = (t >> 4) & 3, wv = t >> 6;

    const int mt_w = am >> 4;
    const int lA1  = (am & 15) + ((aq >> 1) << 4);
    const int lA2  = (am & 15) + ((2 + (aq >> 1)) << 4);
    const int j0   = (aq & 1) * 4;
    const int nb0  = wv * NTN;

    f32x4 acc[4][NTN];
#pragma unroll
    for (int mt = 0; mt < 4; mt++)
#pragma unroll
        for (int nt = 0; nt < NTN; nt++) acc[mt][nt] = (f32x4)0.f;

    for (int ti = 0; ti < NT; ti++) {
        // stage A (own row)
        {
            const int gk0 = ti * 32 + 4 * aq;
            float4 v0 = make_float4(0.f, 0.f, 0.f, 0.f);
            float4 v1 = v0;
            if (anode >= 0) {
                const float* r = (gk0 < 128) ? buf0 + (size_t)anode * 128 + gk0
                                             : buf1 + (size_t)anode * 128 + (gk0 - 128);
                v0 = *(const float4*)r;
                v1 = *(const float4*)(r + 16);
            }
            const float g[8] = {v0.x, v0.y, v0.z, v0.w, v1.x, v1.y, v1.z, v1.w};
            half4 h1, l1, h2, l2;
#pragma unroll
            for (int i = 0; i < 4; i++) {
                const _Float16 h = (_Float16)g[i];
                h1[i] = h; l1[i] = (_Float16)(g[i] - (float)h);
                const _Float16 q = (_Float16)g[4 + i];
                h2[i] = q; l2[i] = (_Float16)(g[4 + i] - (float)q);
            }
            *(half4*)&Ah[mt_w][lA1][j0] = h1;
            *(half4*)&Al[mt_w][lA1][j0] = l1;
            *(half4*)&Ah[mt_w][lA2][j0] = h2;
            *(half4*)&Al[mt_w][lA2][j0] = l2;
        }
        half8 bh[NTN], bl[NTN];
        {
            const size_t tbase = (((size_t)d * NT + ti) * NB) * 512;
#pragma unroll
            for (int nt = 0; nt < NTN; nt++) {
                const size_t off = tbase + (size_t)(nb0 + nt) * 512 + (size_t)am * 8;
                bh[nt] = *(const half8*)(wph + off);
                bl[nt] = *(const half8*)(wpl + off);
            }
        }
        __syncthreads();
        {
            half8 ah[4], alo[4];
#pragma unroll
            for (int mt = 0; mt < 4; mt++) {
                ah[mt]  = *(const half8*)&Ah[mt][am][0];
                alo[mt] = *(const half8*)&Al[mt][am][0];
            }
#pragma unroll
            for (int nt = 0; nt < NTN; nt++)
#pragma unroll
                for (int mt = 0; mt < 4; mt++) {
                    acc[mt][nt] = __builtin_amdgcn_mfma_f32_16x16x32_f16(ah[mt],  bh[nt], acc[mt][nt], 0, 0, 0);
                    acc[mt][nt] = __builtin_amdgcn_mfma_f32_16x16x32_f16(alo[mt], bh[nt], acc[mt][nt], 0, 0, 0);
                    acc[mt][nt] = __builtin_amdgcn_mfma_f32_16x16x32_f16(ah[mt],  bl[nt], acc[mt][nt], 0, 0, 0);
                }
        }
        __syncthreads();
    }

    // epilogue: in-place split write (one block owns its rows end-to-end)
    float blv[NTN], w0[NTN], w1[NTN];
    int cols[NTN];
#pragma unroll
    for (int nt = 0; nt < NTN; nt++) {
        cols[nt] = wv * 64 + nt * 16 + lx;
        blv[nt] = bias[d * COUT + cols[nt]];
        w0[nt]  = Wf[(size_t)(256 + cols[nt]) * 2 + 0];
        w1[nt]  = Wf[(size_t)(256 + cols[nt]) * 2 + 1];
    }
#pragma unroll
    for (int mt = 0; mt < 4; mt++)
#pragma unroll
    for (int r = 0; r < 4; r++) {
        const int node = rowid[mt * 16 + qd * 4 + r];
        float p0 = 0.f, p1 = 0.f;
        if (node >= 0) {
#pragma unroll
            for (int nt = 0; nt < NTN; nt++) {
                const float h = acc[mt][nt][r] + blv[nt];
                p0 = fmaf(h, w0[nt], p0);
                p1 = fmaf(h, w1[nt], p1);
                if (cols[nt] < 128) buf0[(size_t)node * 128 + cols[nt]] = h;
                else                buf1[(size_t)node * 128 + cols[nt] - 128] = h;
            }
        }
#pragma unroll
        for (int s = 1; s < 16; s <<= 1) {
            p0 += __shfl_xor(p0, s, 64);
            p1 += __shfl_xor(p1, s, 64);
        }
        if (node >= 0 && lx == 0) {
            atomicAdd(&logits[(size_t)node * 2 + 0], p0);
            atomicAdd(&logits[(size_t)node * 2 + 1], p1);
        }
    }
}

// ---------------- pooling / output ----------------

__global__ void k_pool_logits(const float* __restrict__ pool, const float* __restrict__ Wf,
                              const float* __restrict__ bf, float* __restrict__ pl) {
    int g = blockIdx.x * 4 + (threadIdx.x >> 6);
    int lane = threadIdx.x & 63;
    const float* pr = pool + (size_t)g * 256;
    float p0 = 0.f, p1 = 0.f;
#pragma unroll
    for (int j = 0; j < 4; j++) {
        int k = lane + 64 * j;
        float v = pr[k];
        p0 = fmaf(v, Wf[(size_t)(768 + k) * 2 + 0], p0);
        p1 = fmaf(v, Wf[(size_t)(768 + k) * 2 + 1], p1);
    }
#pragma unroll
    for (int s = 1; s < 64; s <<= 1) {
        p0 += __shfl_xor(p0, s, 64);
        p1 += __shfl_xor(p1, s, 64);
    }
    if (lane == 0) {
        pl[(size_t)g * 2 + 0] = p0 + bf[0];
        pl[(size_t)g * 2 + 1] = p1 + bf[1];
    }
}

__global__ void k_final(const float* __restrict__ logits, const float* __restrict__ pl,
                        const int* __restrict__ batch, float* __restrict__ outp) {
    int i = blockIdx.x * 256 + threadIdx.x;
    if (i < NN) {
        int g = batch[i];
        float l0 = logits[(size_t)i * 2 + 0] + pl[(size_t)g * 2 + 0];
        float l1 = logits[(size_t)i * 2 + 1] + pl[(size_t)g * 2 + 1];
        float m = fmaxf(l0, l1);
        float e0 = expf(l0 - m), e1 = expf(l1 - m);
        float inv = 1.f / (e0 + e1);
        outp[(size_t)i * 2 + 0] = e0 * inv;
        outp[(size_t)i * 2 + 1] = e1 * inv;
    }
}

}  // namespace

extern "C" void kernel_launch(void* const* d_in, const int* in_sizes, int n_in,
                              void* d_out, int out_size, void* d_ws, size_t ws_size,
                              hipStream_t stream) {
    const float* x     = (const float*)d_in[0];
    const int*   ei    = (const int*)d_in[1];
    const int*   batch = (const int*)d_in[2];
    const float* Wl0 = (const float*)d_in[3];  const float* bl0 = (const float*)d_in[4];
    const float* Wr0 = (const float*)d_in[5];
    const float* Wl1 = (const float*)d_in[6];  const float* bl1 = (const float*)d_in[7];
    const float* Wr1 = (const float*)d_in[8];
    const float* Wl2 = (const float*)d_in[9];  const float* bl2 = (const float*)d_in[10];
    const float* Wr2 = (const float*)d_in[11];
    const float* Wl3 = (const float*)d_in[12]; const float* bl3 = (const float*)d_in[13];
    const float* Wr3 = (const float*)d_in[14];
    const float* Wf  = (const float*)d_in[15]; const float* bf  = (const float*)d_in[16];
    const int* src = ei;
    const int* dst = ei + NE;
    float* outp = (float*)d_out;
    (void)in_sizes; (void)n_in;

    // workspace bump allocator (256B aligned).  Total ≈ 224 MB (ws is 256 MB).
    char* w = (char*)d_ws;
    auto alloc = [&](size_t bytes) -> void* {
        void* p = (void*)w;
        w += (bytes + 255) & ~(size_t)255;
        return p;
    };
    // zero-init region (contiguous): deg .. pool
    int*   deg    = (int*)alloc((size_t)NN * 4);
    float* logits = (float*)alloc((size_t)NN * 2 * 4);
    float* pool   = (float*)alloc((size_t)NG * 256 * 4);
    size_t zero_words = (size_t)(w - (char*)deg) / 4;
    // fully-written-by-kernel regions
    int*   bpad    = (int*)alloc(32);
    int*   blkcnt  = (int*)alloc((size_t)6 * NBC * 4);
    int*   perm    = (int*)alloc((size_t)PERMN * 4);      // filled with -1
    int*   row_ptr = (int*)alloc((size_t)(NN + 1) * 4);
    int*   cursor  = (int*)alloc((size_t)NN * 4);
    int*   col     = (int*)alloc((size_t)NE * 4);
    int*   part    = (int*)alloc(1024 * 4);
    float* pl      = (float*)alloc((size_t)NG * 2 * 4);
    _Float16* whi  = (_Float16*)alloc(WTOT * 2);          // packed weights hi
    _Float16* wlo  = (_Float16*)alloc(WTOT * 2);          // packed weights lo
    float* bufA    = (float*)alloc((size_t)NN * 128 * 4); // h0 -> m2 -> h2[:,0:128)
    float* bufB    = (float*)alloc((size_t)NN * 128 * 4); // h1 -> h2[:,128:256)

    size_t required = (size_t)(w - (char*)d_ws);
    if (required > ws_size) {
        k_report<<<(out_size + 255) / 256, 256, 0, stream>>>(
            outp, (float)(double)(ws_size >> 20), out_size);
        return;
    }

    dim3 b256(256);
    k_memset32<<<(int)((zero_words + 255) / 256), b256, 0, stream>>>((int*)deg, 0, (int)zero_words);
    k_memset32<<<(PERMN + 255) / 256, b256, 0, stream>>>(perm, -1, PERMN);

    // pack all weights into fragment-ordered f16 hi/lo
    k_wpack<64, 128><<<(int)(P_L0 / 8 + 255) / 256, b256, 0, stream>>>(Wl0, Wr0, whi + O_P0, wlo + O_P0);
    k_wpack<128, 128><<<(int)(P_L1 / 8 + 255) / 256, b256, 0, stream>>>(Wl1, Wr1, whi + O_P1, wlo + O_P1);
    k_wpack<128, 256><<<(int)(P_L2 / 8 + 255) / 256, b256, 0, stream>>>(Wl2, Wr2, whi + O_P2, wlo + O_P2);
    k_wpack<256, 256><<<(int)(P_L3 / 8 + 255) / 256, b256, 0, stream>>>(Wl3, Wr3, whi + O_P3, wlo + O_P3);

    k_count_deg<<<NE / 256, b256, 0, stream>>>(dst, deg);
    k_scan_part<<<NBC, b256, 0, stream>>>(deg, part);
    k_scan_single<<<1, 1024, 0, stream>>>(part, NBC);
    k_scan_final<<<NBC, b256, 0, stream>>>(deg, part, row_ptr, cursor);
    k_fill_csr<<<NE / 256, b256, 0, stream>>>(src, dst, cursor, col);
    k_bucket_blockcount<<<NBC, b256, 0, stream>>>(deg, blkcnt);
    k_bucket_scanall<<<1, 64, 0, stream>>>(blkcnt, bpad);
    k_scatter2<<<NBC, b256, 0, stream>>>(deg, blkcnt, bpad, perm);

    // Layer 0: in=x(64) -> h0=bufA(128)
    k_transform<64, 0, 128, 128, false><<<dim3(NBLK, 1), b256, 0, stream>>>(
        x, nullptr, row_ptr, col, whi + O_P0, wlo + O_P0,
        bl0, Wf, perm, deg, nullptr, bufA, nullptr, logits, 0);
    // Layer 1: in=bufA(128) -> h1=bufB(128)
    k_transform<128, 0, 128, 128, false><<<dim3(NBLK, 1), b256, 0, stream>>>(
        bufA, nullptr, row_ptr, col, whi + O_P1, wlo + O_P1,
        bl1, Wf, perm, deg, nullptr, bufB, nullptr, logits, 128);
    // Layer 2a: m2 = gather-sum(h1) -> bufA
    k_aggregate128<<<NN / 4, b256, 0, stream>>>(bufB, row_ptr, col, bufA);
    // Layer 2b: h2 = [m2|h1] @ [Wl2;Wr2] + bl2, in place -> [bufA|bufB]
    k_gemm2b<<<dim3(NBLK), b256, 0, stream>>>(
        bufA, bufB, whi + O_P2, wlo + O_P2, bl2, Wf, perm, deg, logits);
    // Layer 3: in=[bufA|bufB](256) -> logits chunk + pool (h3 never stored)
    k_transform<128, 128, 256, 256, true><<<dim3(NBLK, 1), b256, 0, stream>>>(
        bufA, bufB, row_ptr, col, whi + O_P3, wlo + O_P3,
        bl3, Wf, perm, deg, batch, nullptr, pool, logits, 512);

    k_pool_logits<<<NG / 4, b256, 0, stream>>>(pool, Wf, bf, pl);
    k_final<<<NBC, b256, 0, stream>>>(logits, pl, batch, outp);
}